// Round 1
// baseline (1336.421 us; speedup 1.0000x reference)
//
#include <hip/hip_runtime.h>

#define NB   4
#define SEQ  1024
#define HID  768
#define NH   12
#define HD   64
// dist index offset: l - r + (MAX_POS-1) = l - r + 1023

// ------------------------------------------------------------------
// QKV projection: out = X @ W + b, written in [B, NH, S, HD] layout.
// X: [4096, 768] row-major. W: [768, 768] row-major. 64x64 tile, 4x4 micro.
// ------------------------------------------------------------------
__global__ __launch_bounds__(256) void qkv_gemm(
    const float* __restrict__ X,
    const float* __restrict__ Wq, const float* __restrict__ bq,
    const float* __restrict__ Wk, const float* __restrict__ bk,
    const float* __restrict__ Wv, const float* __restrict__ bv,
    float* __restrict__ qkv)
{
    __shared__ float Xs[16][68];   // [k][m], padded to dodge transpose-write conflicts
    __shared__ float Ws[16][64];   // [k][n]

    const int z = blockIdx.z;
    const float* __restrict__ W    = (z == 0) ? Wq : (z == 1) ? Wk : Wv;
    const float* __restrict__ bias = (z == 0) ? bq : (z == 1) ? bk : bv;
    float* __restrict__ out = qkv + (size_t)z * NB * SEQ * HID;

    const int tid = threadIdx.x;
    const int m0 = blockIdx.x * 64;
    const int n0 = blockIdx.y * 64;
    const int tm = (tid >> 4) << 2;   // 0..60
    const int tn = (tid & 15) << 2;   // 0..60

    float acc[4][4] = {};

    for (int k0 = 0; k0 < HID; k0 += 16) {
        {   // stage X tile 64x16 (transposed into Xs[k][m])
            const int row = tid >> 2;
            const int kq  = (tid & 3) << 2;
            const float4 x = *(const float4*)&X[(size_t)(m0 + row) * HID + k0 + kq];
            Xs[kq + 0][row] = x.x;
            Xs[kq + 1][row] = x.y;
            Xs[kq + 2][row] = x.z;
            Xs[kq + 3][row] = x.w;
        }
        {   // stage W tile 16x64
            const int kr = tid >> 4;
            const int nq = (tid & 15) << 2;
            *(float4*)&Ws[kr][nq] = *(const float4*)&W[(size_t)(k0 + kr) * HID + n0 + nq];
        }
        __syncthreads();
        #pragma unroll
        for (int k = 0; k < 16; ++k) {
            const float4 a = *(const float4*)&Xs[k][tm];
            const float4 b = *(const float4*)&Ws[k][tn];
            const float av[4] = {a.x, a.y, a.z, a.w};
            const float bv4[4] = {b.x, b.y, b.z, b.w};
            #pragma unroll
            for (int i = 0; i < 4; ++i)
                #pragma unroll
                for (int j = 0; j < 4; ++j)
                    acc[i][j] += av[i] * bv4[j];
        }
        __syncthreads();
    }

    const int h = n0 >> 6;  // n0 multiple of 64 -> fixed head per column-tile
    #pragma unroll
    for (int i = 0; i < 4; ++i) {
        const int m  = m0 + tm + i;
        const int bb = m >> 10;       // SEQ = 1024
        const int ss = m & 1023;
        float4 o;
        o.x = acc[i][0] + bias[n0 + tn + 0];
        o.y = acc[i][1] + bias[n0 + tn + 1];
        o.z = acc[i][2] + bias[n0 + tn + 2];
        o.w = acc[i][3] + bias[n0 + tn + 3];
        *(float4*)&out[(((size_t)bb * NH + h) * SEQ + ss) * HD + tn] = o;
    }
}

// ------------------------------------------------------------------
// Fused attention with relative_key_query bias, flash-style.
// Block: 256 threads, one (b,h) and 64 query rows. Loop over 16 k-tiles.
// Thread t owns query row li = t/4 and r-offsets {lane4 + 4i}, i=0..15,
// accumulating the FULL 64-col output row over its r-subset; 4-lane
// shuffle reduce at the end.
// score(l,r) = [ q·k + (q+k)·E[l-r+1023] ] / 8 + mask[b,r]
// ------------------------------------------------------------------
#define EPAD 68

__global__ __launch_bounds__(256) void attn_kernel(
    const float* __restrict__ q,
    const float* __restrict__ k,
    const float* __restrict__ v,
    const float* __restrict__ E,      // dist_emb [2047, 64]
    const float* __restrict__ mask,   // [B,1,1,S]
    float* __restrict__ out)          // [B, S, HID]
{
    __shared__ float Qs[64][EPAD];
    __shared__ float Ks[64][EPAD];
    __shared__ float Vs[64][EPAD];
    __shared__ float Eb[127][EPAD];
    __shared__ float Ms[64];

    const int tid = threadIdx.x;
    const int l0  = blockIdx.x * 64;
    const int bh  = blockIdx.y;          // b*NH + h
    const int b   = bh / NH;

    const float* __restrict__ qb = q + (size_t)bh * SEQ * HD;
    const float* __restrict__ kb = k + (size_t)bh * SEQ * HD;
    const float* __restrict__ vb = v + (size_t)bh * SEQ * HD;

    const int li    = tid >> 2;   // query row within tile, 0..63
    const int lane4 = tid & 3;    // r-subset selector

    // stage Q tile once (consumed after first barrier in the loop)
    #pragma unroll
    for (int ii = 0; ii < 4; ++ii) {
        const int idx = tid + 256 * ii;     // float4 index, 0..1023
        const int row = idx >> 4;
        const int c4  = (idx & 15) << 2;
        *(float4*)&Qs[row][c4] = *(const float4*)&qb[(size_t)(l0 + row) * HD + c4];
    }

    float4 O[16];
    #pragma unroll
    for (int j = 0; j < 16; ++j) O[j] = make_float4(0.f, 0.f, 0.f, 0.f);
    float m_run = -1e30f;
    float lsum  = 0.f;

    for (int r0 = 0; r0 < SEQ; r0 += 64) {
        __syncthreads();   // previous tile fully consumed (also covers Q staging)

        // stage K, V tiles
        #pragma unroll
        for (int ii = 0; ii < 4; ++ii) {
            const int idx = tid + 256 * ii;
            const int row = idx >> 4;
            const int c4  = (idx & 15) << 2;
            *(float4*)&Ks[row][c4] = *(const float4*)&kb[(size_t)(r0 + row) * HD + c4];
            *(float4*)&Vs[row][c4] = *(const float4*)&vb[(size_t)(r0 + row) * HD + c4];
        }
        // stage E band: rows jbase .. jbase+126 ; jbase in [0, 1920]
        const int jbase = l0 - r0 + 960;
        #pragma unroll
        for (int ii = 0; ii < 8; ++ii) {
            const int idx = tid + 256 * ii;   // 0..2047, need 0..2031
            if (idx < 127 * 16) {
                const int row = idx >> 4;
                const int c4  = (idx & 15) << 2;
                *(float4*)&Eb[row][c4] = *(const float4*)&E[(size_t)(jbase + row) * HD + c4];
            }
        }
        if (tid < 64) Ms[tid] = mask[(size_t)b * SEQ + r0 + tid];
        __syncthreads();

        // ---- scores: sc[i] for r = r0 + lane4 + 4i ----
        float sc[16];
        #pragma unroll
        for (int i = 0; i < 16; ++i) sc[i] = 0.f;

        #pragma unroll 2
        for (int d4 = 0; d4 < 16; ++d4) {
            const float4 qv = *(const float4*)&Qs[li][d4 << 2];
            #pragma unroll
            for (int i = 0; i < 16; ++i) {
                const int ro = lane4 + (i << 2);
                const float4 kv = *(const float4*)&Ks[ro][d4 << 2];
                const float4 ev = *(const float4*)&Eb[li - ro + 63][d4 << 2];
                sc[i] += qv.x * kv.x + qv.y * kv.y + qv.z * kv.z + qv.w * kv.w
                       + (qv.x + kv.x) * ev.x + (qv.y + kv.y) * ev.y
                       + (qv.z + kv.z) * ev.z + (qv.w + kv.w) * ev.w;
            }
        }

        // ---- online softmax update ----
        float tmax = -1e30f;
        #pragma unroll
        for (int i = 0; i < 16; ++i) {
            sc[i] = sc[i] * 0.125f + Ms[lane4 + (i << 2)];
            tmax = fmaxf(tmax, sc[i]);
        }
        tmax = fmaxf(tmax, __shfl_xor(tmax, 1));
        tmax = fmaxf(tmax, __shfl_xor(tmax, 2));
        const float m_new = fmaxf(m_run, tmax);
        const float corr  = __expf(m_run - m_new);

        float p[16];
        float tsum = 0.f;
        #pragma unroll
        for (int i = 0; i < 16; ++i) {
            p[i] = __expf(sc[i] - m_new);
            tsum += p[i];
        }
        tsum += __shfl_xor(tsum, 1);
        tsum += __shfl_xor(tsum, 2);
        lsum  = lsum * corr + tsum;
        m_run = m_new;

        #pragma unroll
        for (int j = 0; j < 16; ++j) {
            O[j].x *= corr; O[j].y *= corr; O[j].z *= corr; O[j].w *= corr;
        }

        // ---- PV: O[l, :] += sum_{r in subset} p * V[r, :] ----
        #pragma unroll 4
        for (int i = 0; i < 16; ++i) {
            const int ro = lane4 + (i << 2);
            const float pi = p[i];
            #pragma unroll
            for (int j = 0; j < 16; ++j) {
                const float4 vv = *(const float4*)&Vs[ro][j << 2];
                O[j].x += pi * vv.x; O[j].y += pi * vv.y;
                O[j].z += pi * vv.z; O[j].w += pi * vv.w;
            }
        }
    }

    // reduce O over the 4 lanes sharing this query row
    #pragma unroll
    for (int j = 0; j < 16; ++j) {
        O[j].x += __shfl_xor(O[j].x, 1); O[j].x += __shfl_xor(O[j].x, 2);
        O[j].y += __shfl_xor(O[j].y, 1); O[j].y += __shfl_xor(O[j].y, 2);
        O[j].z += __shfl_xor(O[j].z, 1); O[j].z += __shfl_xor(O[j].z, 2);
        O[j].w += __shfl_xor(O[j].w, 1); O[j].w += __shfl_xor(O[j].w, 2);
    }
    const float inv = 1.0f / lsum;   // lsum identical across the 4 lanes

    const int h = bh - b * NH;
    const size_t obase = ((size_t)b * SEQ + l0 + li) * HID + (size_t)h * HD;
    #pragma unroll
    for (int jj = 0; jj < 4; ++jj) {
        const int j = (lane4 << 2) + jj;   // each lane writes a 16-col quarter
        float4 o = O[j];
        o.x *= inv; o.y *= inv; o.z *= inv; o.w *= inv;
        *(float4*)&out[obase + (j << 2)] = o;
    }
}

// ------------------------------------------------------------------
extern "C" void kernel_launch(void* const* d_in, const int* in_sizes, int n_in,
                              void* d_out, int out_size, void* d_ws, size_t ws_size,
                              hipStream_t stream) {
    const float* hidden = (const float*)d_in[0];
    const float* mask   = (const float*)d_in[1];
    const float* Wq     = (const float*)d_in[2];
    const float* bq     = (const float*)d_in[3];
    const float* Wk     = (const float*)d_in[4];
    const float* bk     = (const float*)d_in[5];
    const float* Wv     = (const float*)d_in[6];
    const float* bv     = (const float*)d_in[7];
    const float* E      = (const float*)d_in[8];
    float* out = (float*)d_out;

    float* qkv = (float*)d_ws;   // q,k,v each [B, NH, S, HD] = 12.58 MB fp32

    dim3 g1(NB * SEQ / 64, HID / 64, 3);   // (64, 12, 3)
    qkv_gemm<<<g1, 256, 0, stream>>>(hidden, Wq, bq, Wk, bk, Wv, bv, qkv);

    const size_t per = (size_t)NB * SEQ * HID;
    dim3 g2(SEQ / 64, NB * NH);            // (16, 48)
    attn_kernel<<<g2, 256, 0, stream>>>(qkv, qkv + per, qkv + 2 * per, E, mask, out);
}

// Round 2
// 243.763 us; speedup vs baseline: 5.4825x; 5.4825x over previous
//
#include <hip/hip_runtime.h>

#define SEQ 1024
#define NH  12
#define HD  64
#define HID 768
#define NB  4

typedef short bf16x8 __attribute__((ext_vector_type(8)));
typedef float f32x16 __attribute__((ext_vector_type(16)));

__device__ __forceinline__ unsigned short f2b(float f) {
    union { float f; unsigned u; } v; v.f = f;
    unsigned r = (v.u + 0x7FFFu + ((v.u >> 16) & 1u)) >> 16;
    return (unsigned short)r;
}
__device__ __forceinline__ float b2f(unsigned short s) {
    union { unsigned u; float f; } v; v.u = (unsigned)s << 16;
    return v.f;
}

// C/D layout for v_mfma_f32_32x32x16_bf16: col = lane&31, row = ROWFN(reg, lane>>5)
#define ROWFN(r, h) (((r) & 3) + 8 * ((r) >> 2) + 4 * (h))

// ------------------------------------------------------------------
// fp32 -> bf16 conversion (grid-stride, float4 in / ushort4 out)
// ------------------------------------------------------------------
__global__ void cvt_bf16(const float* __restrict__ in, unsigned short* __restrict__ outp, int n4) {
    int i = blockIdx.x * blockDim.x + threadIdx.x;
    const int stride = gridDim.x * blockDim.x;
    for (; i < n4; i += stride) {
        float4 v = ((const float4*)in)[i];
        ushort4 o;
        o.x = f2b(v.x); o.y = f2b(v.y); o.z = f2b(v.z); o.w = f2b(v.w);
        ((ushort4*)outp)[i] = o;
    }
}

// ------------------------------------------------------------------
// W [768][768] fp32 -> Wt [768 n][768 k] bf16 (transposed), 64x64 tiles
// ------------------------------------------------------------------
__global__ __launch_bounds__(256) void cvt_wt(
    const float* __restrict__ Wq, const float* __restrict__ Wk, const float* __restrict__ Wv,
    unsigned short* __restrict__ Wt)
{
    __shared__ float T[64][65];
    const int z = blockIdx.z;
    const float* __restrict__ W = (z == 0) ? Wq : (z == 1) ? Wk : Wv;
    const int k0 = blockIdx.x * 64, n0 = blockIdx.y * 64;
    const int tid = threadIdx.x;
    #pragma unroll
    for (int ir = 0; ir < 4; ++ir) {
        int r = ir * 16 + (tid >> 4);
        int c4 = (tid & 15) * 4;
        *(float4*)&T[r][c4] = *(const float4*)&W[(size_t)(k0 + r) * HID + n0 + c4];
    }
    __syncthreads();
    const int cc = tid >> 2, q = tid & 3;
    unsigned short* dst = Wt + (size_t)z * HID * HID + (size_t)(n0 + cc) * HID + k0 + q * 16;
    #pragma unroll
    for (int j4 = 0; j4 < 4; ++j4) {
        ushort4 t4;
        t4.x = f2b(T[q * 16 + j4 * 4 + 0][cc]);
        t4.y = f2b(T[q * 16 + j4 * 4 + 1][cc]);
        t4.z = f2b(T[q * 16 + j4 * 4 + 2][cc]);
        t4.w = f2b(T[q * 16 + j4 * 4 + 3][cc]);
        *(ushort4*)(dst + j4 * 4) = t4;
    }
}

// ------------------------------------------------------------------
// QKV GEMM (bf16 MFMA): qkv[z] = Xbf @ W[z] + b[z], out bf16 [z][B,NH,S,HD]
// 128x128 tile, BK=64, 4 waves (one 64x64 quadrant each, 2x2 of 32x32 frags)
// ------------------------------------------------------------------
__global__ __launch_bounds__(256) void gemm_qkv(
    const unsigned short* __restrict__ Xb,   // [4096][768] bf16
    const unsigned short* __restrict__ Wt,   // [3][768 n][768 k] bf16
    const float* __restrict__ bq, const float* __restrict__ bk, const float* __restrict__ bv,
    unsigned short* __restrict__ qkv)        // [3][48][1024][64] bf16
{
    __shared__ unsigned short Xs[128][64];   // XOR-swizzled 16B slots
    __shared__ unsigned short Ws[128][64];

    const int tid = threadIdx.x;
    const int lane = tid & 63;
    const int wid = tid >> 6;
    const int c = lane & 31;
    const int h2 = lane >> 5;
    const int m0 = blockIdx.x * 128, N0 = blockIdx.y * 128, z = blockIdx.z;
    const unsigned short* __restrict__ Wz = Wt + (size_t)z * HID * HID;
    const float* __restrict__ bias = (z == 0) ? bq : (z == 1) ? bk : bv;

    f32x16 acc[2][2];
    #pragma unroll
    for (int i = 0; i < 2; ++i)
        #pragma unroll
        for (int j = 0; j < 2; ++j)
            #pragma unroll
            for (int r = 0; r < 16; ++r) acc[i][j][r] = 0.f;

    for (int k0 = 0; k0 < HID; k0 += 64) {
        __syncthreads();
        #pragma unroll
        for (int it = 0; it < 4; ++it) {
            int t16 = tid + 256 * it;          // 0..1023
            int row = t16 >> 3, s = t16 & 7;
            bf16x8 xv = *(const bf16x8*)(Xb + (size_t)(m0 + row) * HID + k0 + s * 8);
            *(bf16x8*)&Xs[row][(s ^ (row & 7)) * 8] = xv;
            bf16x8 wv = *(const bf16x8*)(Wz + (size_t)(N0 + row) * HID + k0 + s * 8);
            *(bf16x8*)&Ws[row][(s ^ (row & 7)) * 8] = wv;
        }
        __syncthreads();
        #pragma unroll
        for (int kc = 0; kc < 4; ++kc) {
            const int slot = kc * 2 + h2;
            bf16x8 af[2], bf_[2];
            #pragma unroll
            for (int i = 0; i < 2; ++i) {
                int ar = 64 * (wid >> 1) + 32 * i + c;
                af[i] = *(const bf16x8*)&Xs[ar][(slot ^ (ar & 7)) * 8];
                int br = 64 * (wid & 1) + 32 * i + c;
                bf_[i] = *(const bf16x8*)&Ws[br][(slot ^ (br & 7)) * 8];
            }
            #pragma unroll
            for (int i = 0; i < 2; ++i)
                #pragma unroll
                for (int j = 0; j < 2; ++j)
                    acc[i][j] = __builtin_amdgcn_mfma_f32_32x32x16_bf16(af[i], bf_[j], acc[i][j], 0, 0, 0);
        }
    }

    // epilogue: bias + cvt + scatter to [B,NH,S,HD]
    #pragma unroll
    for (int j = 0; j < 2; ++j) {
        const int n = N0 + 64 * (wid & 1) + 32 * j + c;
        const float bv_ = bias[n];
        const int hh = n >> 6, d = n & 63;
        #pragma unroll
        for (int i = 0; i < 2; ++i) {
            #pragma unroll
            for (int r = 0; r < 16; ++r) {
                int m = m0 + 64 * (wid >> 1) + 32 * i + ROWFN(r, h2);
                int bb = m >> 10, ss = m & 1023;
                float v = acc[i][j][r] + bv_;
                qkv[(size_t)z * (NB * SEQ * HID)
                    + (((size_t)bb * NH + hh) * SEQ + ss) * HD + d] = f2b(v);
            }
        }
    }
}

// ------------------------------------------------------------------
// Fused attention, bf16 MFMA, relative_key_query bias.
// Block: 256 thr (4 waves), one (b,h), 64 query rows; loop 16 K/V tiles.
// Per tile: S1 = Q.K^T (64x64), M = Q.Eb^T (64x128), N = K.Eb^T (64x128)
// via MFMA (K,E operands straight from global/L2); softmax by row-threads;
// PV via MFMA (P_lds swizzled, Vt transposed+swizzled in LDS).
// ------------------------------------------------------------------
__global__ __launch_bounds__(256) void attn_mfma(
    const unsigned short* __restrict__ Qg,   // [48][1024][64] bf16
    const unsigned short* __restrict__ Kg,
    const unsigned short* __restrict__ Vg,
    const unsigned short* __restrict__ Eg,   // [2047][64] bf16
    const float* __restrict__ mask,          // [4][1024]
    float* __restrict__ out)                 // [4][1024][768] fp32
{
    __shared__ unsigned short Vt[64][64];    // [d][r], swizzled slots
    __shared__ float S1[64][68];
    __shared__ unsigned short Mt[128][68];   // M^T: [j][l] bf16
    __shared__ unsigned short Nt[128][68];   // N^T: [j][r] bf16
    __shared__ unsigned short Pl[64][64];    // P: [l][r] bf16, swizzled slots
    __shared__ float Corr[64];
    __shared__ float InvL[64];

    const int tid = threadIdx.x;
    const int lane = tid & 63;
    const int wid = tid >> 6;
    const int c = lane & 31;
    const int h2 = lane >> 5;
    const int RB = 32 * (wid >> 1);          // row block (Q rows / K rows for N)
    const int CB = 32 * (wid & 1);           // col block (K rows for S1 / d for PV)

    const int l0 = blockIdx.x * 64;
    const int bh = blockIdx.y;
    const int b = bh / NH;
    const int hh = bh - b * NH;

    const unsigned short* __restrict__ Qb = Qg + (size_t)bh * SEQ * HD;
    const unsigned short* __restrict__ Kb = Kg + (size_t)bh * SEQ * HD;
    const unsigned short* __restrict__ Vb = Vg + (size_t)bh * SEQ * HD;

    // Q A-fragments: held in registers for the whole block
    bf16x8 qa[4];
    #pragma unroll
    for (int kc = 0; kc < 4; ++kc)
        qa[kc] = *(const bf16x8*)(Qb + (size_t)(l0 + RB + c) * HD + kc * 16 + h2 * 8);

    f32x16 Oa;
    #pragma unroll
    for (int r = 0; r < 16; ++r) Oa[r] = 0.f;

    const int li = tid >> 2;                 // softmax: owned row
    const int c0q = (tid & 3) * 16;          // softmax: 16 owned cols
    float m_run = -1e30f, lsum = 0.f;

    for (int r0 = 0; r0 < SEQ; r0 += 64) {
        __syncthreads();                     // prev tile's LDS consumers done

        // ---- stage Vt (transpose + swizzle) ----
        #pragma unroll
        for (int it = 0; it < 2; ++it) {
            int idx = tid + 256 * it;        // 0..511
            int r = idx & 63, d0 = (idx >> 6) * 8;
            bf16x8 vv = *(const bf16x8*)(Vb + (size_t)(r0 + r) * HD + d0);
            #pragma unroll
            for (int e = 0; e < 8; ++e) {
                int d = d0 + e;
                int sl = (r >> 3) ^ (d & 7);
                Vt[d][sl * 8 + (r & 7)] = (unsigned short)vv[e];
            }
        }

        // ---- phase c: MFMA S1 / M / N (K, E operands from global/L2) ----
        const int jbase = l0 - r0 + 960;
        bf16x8 kbf[4], kaf[4];
        #pragma unroll
        for (int kc = 0; kc < 4; ++kc) {
            kbf[kc] = *(const bf16x8*)(Kb + (size_t)(r0 + CB + c) * HD + kc * 16 + h2 * 8);
            kaf[kc] = *(const bf16x8*)(Kb + (size_t)(r0 + RB + c) * HD + kc * 16 + h2 * 8);
        }
        f32x16 s1a, ma0, ma1, na0, na1;
        #pragma unroll
        for (int r = 0; r < 16; ++r) { s1a[r] = 0.f; ma0[r] = 0.f; ma1[r] = 0.f; na0[r] = 0.f; na1[r] = 0.f; }

        #pragma unroll
        for (int kc = 0; kc < 4; ++kc)
            s1a = __builtin_amdgcn_mfma_f32_32x32x16_bf16(qa[kc], kbf[kc], s1a, 0, 0, 0);

        #pragma unroll
        for (int kc = 0; kc < 4; ++kc) {
            int jr0 = jbase + 64 * (wid & 1) + c;
            int jra = (jr0 > 2046) ? 2046 : jr0;
            bf16x8 eb0 = *(const bf16x8*)(Eg + (size_t)jra * HD + kc * 16 + h2 * 8);
            ma0 = __builtin_amdgcn_mfma_f32_32x32x16_bf16(qa[kc], eb0, ma0, 0, 0, 0);
            na0 = __builtin_amdgcn_mfma_f32_32x32x16_bf16(kaf[kc], eb0, na0, 0, 0, 0);
            int jr1 = jr0 + 32;
            int jrb = (jr1 > 2046) ? 2046 : jr1;
            bf16x8 eb1 = *(const bf16x8*)(Eg + (size_t)jrb * HD + kc * 16 + h2 * 8);
            ma1 = __builtin_amdgcn_mfma_f32_32x32x16_bf16(qa[kc], eb1, ma1, 0, 0, 0);
            na1 = __builtin_amdgcn_mfma_f32_32x32x16_bf16(kaf[kc], eb1, na1, 0, 0, 0);
        }

        // write S1 (fp32) + Mt/Nt (bf16 packed b64)
        #pragma unroll
        for (int r = 0; r < 16; ++r)
            S1[RB + ROWFN(r, h2)][CB + c] = s1a[r];
        {
            const int jc0 = 64 * (wid & 1) + c;
            #pragma unroll
            for (int q = 0; q < 4; ++q) {
                const int lb = RB + 8 * q + 4 * h2;
                ushort4 mw, nw;
                mw.x = f2b(ma0[4 * q + 0]); mw.y = f2b(ma0[4 * q + 1]);
                mw.z = f2b(ma0[4 * q + 2]); mw.w = f2b(ma0[4 * q + 3]);
                nw.x = f2b(na0[4 * q + 0]); nw.y = f2b(na0[4 * q + 1]);
                nw.z = f2b(na0[4 * q + 2]); nw.w = f2b(na0[4 * q + 3]);
                *(ushort4*)&Mt[jc0][lb] = mw;
                *(ushort4*)&Nt[jc0][lb] = nw;
                ushort4 mw1, nw1;
                mw1.x = f2b(ma1[4 * q + 0]); mw1.y = f2b(ma1[4 * q + 1]);
                mw1.z = f2b(ma1[4 * q + 2]); mw1.w = f2b(ma1[4 * q + 3]);
                nw1.x = f2b(na1[4 * q + 0]); nw1.y = f2b(na1[4 * q + 1]);
                nw1.z = f2b(na1[4 * q + 2]); nw1.w = f2b(na1[4 * q + 3]);
                *(ushort4*)&Mt[jc0 + 32][lb] = mw1;
                *(ushort4*)&Nt[jc0 + 32][lb] = nw1;
            }
        }
        __syncthreads();                     // S1/Mt/Nt visible

        // ---- softmax: thread owns row li, cols c0q..c0q+15 ----
        float sc[16];
        #pragma unroll
        for (int q4 = 0; q4 < 4; ++q4) {
            float4 s4 = *(const float4*)&S1[li][c0q + q4 * 4];
            sc[q4 * 4 + 0] = s4.x; sc[q4 * 4 + 1] = s4.y;
            sc[q4 * 4 + 2] = s4.z; sc[q4 * 4 + 3] = s4.w;
        }
        float msk[16];
        {
            const float* mrow = mask + (size_t)b * SEQ + r0 + c0q;
            #pragma unroll
            for (int q4 = 0; q4 < 4; ++q4) {
                float4 m4 = *(const float4*)(mrow + q4 * 4);
                msk[q4 * 4 + 0] = m4.x; msk[q4 * 4 + 1] = m4.y;
                msk[q4 * 4 + 2] = m4.z; msk[q4 * 4 + 3] = m4.w;
            }
        }
        #pragma unroll
        for (int j = 0; j < 16; ++j) {
            int rr = c0q + j;
            int jdx = li - rr + 63;
            float mv = b2f(Mt[jdx][li]);
            float nv = b2f(Nt[jdx][rr]);
            sc[j] = (sc[j] + mv + nv) * 0.125f + msk[j];
        }
        float tmax = sc[0];
        #pragma unroll
        for (int j = 1; j < 16; ++j) tmax = fmaxf(tmax, sc[j]);
        tmax = fmaxf(tmax, __shfl_xor(tmax, 1));
        tmax = fmaxf(tmax, __shfl_xor(tmax, 2));
        const float m_new = fmaxf(m_run, tmax);
        const float corr = __expf(m_run - m_new);
        float tsum = 0.f;
        unsigned short pb[16];
        #pragma unroll
        for (int j = 0; j < 16; ++j) {
            float p = __expf(sc[j] - m_new);
            tsum += p;
            pb[j] = f2b(p);
        }
        tsum += __shfl_xor(tsum, 1);
        tsum += __shfl_xor(tsum, 2);
        lsum = lsum * corr + tsum;
        m_run = m_new;
        if ((tid & 3) == 0) Corr[li] = corr;
        #pragma unroll
        for (int sblk = 0; sblk < 2; ++sblk) {
            int sl = ((c0q >> 3) + sblk) ^ (li & 7);
            ushort4 a4, b4;
            a4.x = pb[sblk * 8 + 0]; a4.y = pb[sblk * 8 + 1];
            a4.z = pb[sblk * 8 + 2]; a4.w = pb[sblk * 8 + 3];
            b4.x = pb[sblk * 8 + 4]; b4.y = pb[sblk * 8 + 5];
            b4.z = pb[sblk * 8 + 6]; b4.w = pb[sblk * 8 + 7];
            *(ushort4*)&Pl[li][sl * 8] = a4;
            *(ushort4*)&Pl[li][sl * 8 + 4] = b4;
        }
        __syncthreads();                     // P, Corr visible

        // ---- PV: O = O*corr + P @ V ----
        #pragma unroll
        for (int r = 0; r < 16; ++r)
            Oa[r] *= Corr[RB + ROWFN(r, h2)];
        #pragma unroll
        for (int kc = 0; kc < 4; ++kc) {
            const int kr = kc * 16 + h2 * 8;
            const int slot = kr >> 3;
            const int lrow = RB + c;
            const int drow = CB + c;
            bf16x8 pa = *(const bf16x8*)&Pl[lrow][(slot ^ (lrow & 7)) * 8];
            bf16x8 vb_ = *(const bf16x8*)&Vt[drow][(slot ^ (drow & 7)) * 8];
            Oa = __builtin_amdgcn_mfma_f32_32x32x16_bf16(pa, vb_, Oa, 0, 0, 0);
        }
    }

    if ((tid & 3) == 0) InvL[li] = 1.0f / lsum;
    __syncthreads();
    #pragma unroll
    for (int r = 0; r < 16; ++r) {
        int l = RB + ROWFN(r, h2);
        float o = Oa[r] * InvL[l];
        out[((size_t)b * SEQ + l0 + l) * HID + hh * HD + CB + c] = o;
    }
}

// ------------------------------------------------------------------
extern "C" void kernel_launch(void* const* d_in, const int* in_sizes, int n_in,
                              void* d_out, int out_size, void* d_ws, size_t ws_size,
                              hipStream_t stream) {
    const float* hidden = (const float*)d_in[0];
    const float* mask   = (const float*)d_in[1];
    const float* Wq     = (const float*)d_in[2];
    const float* bq     = (const float*)d_in[3];
    const float* Wk     = (const float*)d_in[4];
    const float* bk     = (const float*)d_in[5];
    const float* Wv     = (const float*)d_in[6];
    const float* bv     = (const float*)d_in[7];
    const float* E      = (const float*)d_in[8];
    float* outp = (float*)d_out;

    unsigned short* ws  = (unsigned short*)d_ws;
    unsigned short* Xbf = ws;                      // 4096*768            = 3145728
    unsigned short* Wt  = ws + 3145728;            // 3*768*768           = 1769472
    unsigned short* Ebf = ws + 4915200;            // 2047*64             = 131008
    unsigned short* qkv = ws + 5046272;            // 3*48*1024*64        = 9437184

    cvt_bf16<<<dim3(1024), 256, 0, stream>>>(hidden, Xbf, 786432);
    cvt_bf16<<<dim3(128),  256, 0, stream>>>(E, Ebf, 32752);
    cvt_wt<<<dim3(12, 12, 3), 256, 0, stream>>>(Wq, Wk, Wv, Wt);
    gemm_qkv<<<dim3(32, 6, 3), 256, 0, stream>>>(Xbf, Wt, bq, bk, bv, qkv);
    attn_mfma<<<dim3(16, 48), 256, 0, stream>>>(qkv, qkv + 3145728, qkv + 6291456,
                                                Ebf, mask, outp);
}

// Round 3
// 187.137 us; speedup vs baseline: 7.1414x; 1.3026x over previous
//
#include <hip/hip_runtime.h>

#define SEQ 1024
#define NH  12
#define HD  64
#define HID 768
#define NB  4

#define LOG2E  1.4426950408889634f
#define SC2    0.18033688011112042f   // 0.125 * log2(e)
#define DTHR   11.541560327111707f    // 8 nats in log2 domain

typedef short bf16x8 __attribute__((ext_vector_type(8)));
typedef float f32x16 __attribute__((ext_vector_type(16)));

__device__ __forceinline__ unsigned short f2b(float f) {
    union { float f; unsigned u; } v; v.f = f;
    unsigned r = (v.u + 0x7FFFu + ((v.u >> 16) & 1u)) >> 16;
    return (unsigned short)r;
}
__device__ __forceinline__ float b2f(unsigned short s) {
    union { unsigned u; float f; } v; v.u = (unsigned)s << 16;
    return v.f;
}
__device__ __forceinline__ float g4(const float4& v, int e) {
    return e == 0 ? v.x : e == 1 ? v.y : e == 2 ? v.z : v.w;
}

// C/D layout for v_mfma_f32_32x32x16_bf16: col = lane&31, row = ROWFN(reg, lane>>5)
#define ROWFN(r, h) (((r) & 3) + 8 * ((r) >> 2) + 4 * (h))

// ------------------------------------------------------------------
// fp32 -> bf16 conversion (grid-stride, float4 in / ushort4 out)
// ------------------------------------------------------------------
__global__ void cvt_bf16(const float* __restrict__ in, unsigned short* __restrict__ outp, int n4) {
    int i = blockIdx.x * blockDim.x + threadIdx.x;
    const int stride = gridDim.x * blockDim.x;
    for (; i < n4; i += stride) {
        float4 v = ((const float4*)in)[i];
        ushort4 o;
        o.x = f2b(v.x); o.y = f2b(v.y); o.z = f2b(v.z); o.w = f2b(v.w);
        ((ushort4*)outp)[i] = o;
    }
}

// ------------------------------------------------------------------
// W [768][768] fp32 -> Wt [768 n][768 k] bf16 (transposed), 64x64 tiles
// ------------------------------------------------------------------
__global__ __launch_bounds__(256) void cvt_wt(
    const float* __restrict__ Wq, const float* __restrict__ Wk, const float* __restrict__ Wv,
    unsigned short* __restrict__ Wt)
{
    __shared__ float T[64][65];
    const int z = blockIdx.z;
    const float* __restrict__ W = (z == 0) ? Wq : (z == 1) ? Wk : Wv;
    const int k0 = blockIdx.x * 64, n0 = blockIdx.y * 64;
    const int tid = threadIdx.x;
    #pragma unroll
    for (int ir = 0; ir < 4; ++ir) {
        int r = ir * 16 + (tid >> 4);
        int c4 = (tid & 15) * 4;
        *(float4*)&T[r][c4] = *(const float4*)&W[(size_t)(k0 + r) * HID + n0 + c4];
    }
    __syncthreads();
    const int cc = tid >> 2, q = tid & 3;
    unsigned short* dst = Wt + (size_t)z * HID * HID + (size_t)(n0 + cc) * HID + k0 + q * 16;
    #pragma unroll
    for (int j4 = 0; j4 < 4; ++j4) {
        ushort4 t4;
        t4.x = f2b(T[q * 16 + j4 * 4 + 0][cc]);
        t4.y = f2b(T[q * 16 + j4 * 4 + 1][cc]);
        t4.z = f2b(T[q * 16 + j4 * 4 + 2][cc]);
        t4.w = f2b(T[q * 16 + j4 * 4 + 3][cc]);
        *(ushort4*)(dst + j4 * 4) = t4;
    }
}

// ------------------------------------------------------------------
// QKV GEMM (bf16 MFMA). z=0,1: out[z] = X@W+b in [bh][s][d] layout.
// z=2: operands SWAPPED -> computes V^T directly, out [bh][d][s] coalesced.
// ------------------------------------------------------------------
__global__ __launch_bounds__(256) void gemm_qkv(
    const unsigned short* __restrict__ Xb,   // [4096][768] bf16
    const unsigned short* __restrict__ Wt,   // [3][768 n][768 k] bf16
    const float* __restrict__ bq, const float* __restrict__ bk, const float* __restrict__ bv,
    unsigned short* __restrict__ qkv)
{
    __shared__ unsigned short Xs[128][64];   // XOR-swizzled 16B slots
    __shared__ unsigned short Ws[128][64];

    const int tid = threadIdx.x;
    const int lane = tid & 63;
    const int wid = tid >> 6;
    const int c = lane & 31;
    const int h2 = lane >> 5;
    const int m0 = blockIdx.x * 128, N0 = blockIdx.y * 128, z = blockIdx.z;
    const unsigned short* __restrict__ Wz = Wt + (size_t)z * HID * HID;
    const float* __restrict__ bias = (z == 0) ? bq : (z == 1) ? bk : bv;

    f32x16 acc[2][2];
    #pragma unroll
    for (int i = 0; i < 2; ++i)
        #pragma unroll
        for (int j = 0; j < 2; ++j)
            #pragma unroll
            for (int r = 0; r < 16; ++r) acc[i][j][r] = 0.f;

    for (int k0 = 0; k0 < HID; k0 += 64) {
        __syncthreads();
        #pragma unroll
        for (int it = 0; it < 4; ++it) {
            int t16 = tid + 256 * it;
            int row = t16 >> 3, s = t16 & 7;
            bf16x8 xv = *(const bf16x8*)(Xb + (size_t)(m0 + row) * HID + k0 + s * 8);
            *(bf16x8*)&Xs[row][(s ^ (row & 7)) * 8] = xv;
            bf16x8 wv = *(const bf16x8*)(Wz + (size_t)(N0 + row) * HID + k0 + s * 8);
            *(bf16x8*)&Ws[row][(s ^ (row & 7)) * 8] = wv;
        }
        __syncthreads();
        #pragma unroll
        for (int kc = 0; kc < 4; ++kc) {
            const int slot = kc * 2 + h2;
            bf16x8 af[2], bf_[2];
            #pragma unroll
            for (int i = 0; i < 2; ++i) {
                int ar = 64 * (wid >> 1) + 32 * i + c;
                int br = 64 * (wid & 1) + 32 * i + c;
                if (z != 2) {
                    af[i]  = *(const bf16x8*)&Xs[ar][(slot ^ (ar & 7)) * 8];
                    bf_[i] = *(const bf16x8*)&Ws[br][(slot ^ (br & 7)) * 8];
                } else {
                    af[i]  = *(const bf16x8*)&Ws[ar][(slot ^ (ar & 7)) * 8];
                    bf_[i] = *(const bf16x8*)&Xs[br][(slot ^ (br & 7)) * 8];
                }
            }
            #pragma unroll
            for (int i = 0; i < 2; ++i)
                #pragma unroll
                for (int j = 0; j < 2; ++j)
                    acc[i][j] = __builtin_amdgcn_mfma_f32_32x32x16_bf16(af[i], bf_[j], acc[i][j], 0, 0, 0);
        }
    }

    unsigned short* outz = qkv + (size_t)z * (NB * SEQ * HID);
    if (z != 2) {
        #pragma unroll
        for (int j = 0; j < 2; ++j) {
            const int n = N0 + 64 * (wid & 1) + 32 * j + c;
            const float bv_ = bias[n];
            const int hh = n >> 6, d = n & 63;
            #pragma unroll
            for (int i = 0; i < 2; ++i) {
                #pragma unroll
                for (int r = 0; r < 16; ++r) {
                    int m = m0 + 64 * (wid >> 1) + 32 * i + ROWFN(r, h2);
                    int bb = m >> 10, ss = m & 1023;
                    outz[(((size_t)bb * NH + hh) * SEQ + ss) * HD + d] = f2b(acc[i][j][r] + bv_);
                }
            }
        }
    } else {
        // acc[i][j]: rows n (A=Wt), cols m (B=X); lane c = col m -> coalesced [bh][d][s]
        #pragma unroll
        for (int i = 0; i < 2; ++i) {
            #pragma unroll
            for (int r = 0; r < 16; ++r) {
                int n = N0 + 64 * (wid >> 1) + 32 * i + ROWFN(r, h2);
                float bv_ = bias[n];
                int hh = n >> 6, d = n & 63;
                #pragma unroll
                for (int j = 0; j < 2; ++j) {
                    int m = m0 + 64 * (wid & 1) + 32 * j + c;
                    int bb = m >> 10, ss = m & 1023;
                    outz[(((size_t)bb * NH + hh) * HD + d) * SEQ + ss] = f2b(acc[i][j][r] + bv_);
                }
            }
        }
    }
}

// ------------------------------------------------------------------
// Fused attention, bf16 MFMA, relative_key_query bias, pipelined.
// ------------------------------------------------------------------
struct PF { bf16x8 kb[4], ka[4], e0[4], e1[4], v0, v1; };

__global__ __launch_bounds__(256, 2) void attn_mfma(
    const unsigned short* __restrict__ Qg,   // [bh][s][d] bf16
    const unsigned short* __restrict__ Kg,   // [bh][s][d] bf16
    const unsigned short* __restrict__ Vtg,  // [bh][d][s] bf16 (pre-transposed)
    const unsigned short* __restrict__ Eg,   // [2047][64] bf16
    const float* __restrict__ mask,          // [4][1024]
    float* __restrict__ out)                 // [4][1024][768] fp32
{
    __shared__ unsigned short Vt[2][64][64]; // [buf][d][r], swizzled 16B slots
    __shared__ float S1T[64 * 64];           // col-major S1, swizzled 16B slots
    __shared__ unsigned short Mt[128][68];   // M^T: [j][l] bf16
    __shared__ unsigned short Nt[128][68];   // N^T: [j][r] bf16
    __shared__ unsigned short Pl[64][64];    // P: [l][r] bf16, swizzled slots
    __shared__ float Corr[64];
    __shared__ float InvL[64];

    const int tid = threadIdx.x;
    const int lane = tid & 63;
    const int wid = tid >> 6;
    const int c = lane & 31;
    const int h2 = lane >> 5;
    const int RB = 32 * (wid >> 1);
    const int CB = 32 * (wid & 1);

    const int l0 = blockIdx.x * 64;
    const int bh = blockIdx.y;
    const int b = bh / NH;
    const int hh = bh - b * NH;

    const unsigned short* __restrict__ Qb = Qg + (size_t)bh * SEQ * HD;
    const unsigned short* __restrict__ Kb = Kg + (size_t)bh * SEQ * HD;
    const unsigned short* __restrict__ Vb = Vtg + (size_t)bh * HD * SEQ;
    const float* __restrict__ mrow_base = mask + (size_t)b * SEQ;

    // persistent Q A-fragments
    bf16x8 qa[4];
    #pragma unroll
    for (int kc = 0; kc < 4; ++kc)
        qa[kc] = *(const bf16x8*)(Qb + (size_t)(l0 + RB + c) * HD + kc * 16 + h2 * 8);

    f32x16 Oa;
    #pragma unroll
    for (int r = 0; r < 16; ++r) Oa[r] = 0.f;

    const int li = tid >> 2;
    const int c0q = (tid & 3) * 16;
    const int kli = (li ^ (li >> 3)) & 7;
    const int vd0 = tid >> 3, vs8 = tid & 7;
    float m_run = -1e30f, lsum = 0.f;

    PF P;
    // ---- prologue prefetch (tile 0) ----
    {
        const int jb = l0 + 960;
        const int jr0 = jb + 64 * (wid & 1) + c;
        #pragma unroll
        for (int kc = 0; kc < 4; ++kc) {
            P.kb[kc] = *(const bf16x8*)(Kb + (size_t)(CB + c) * HD + kc * 16 + h2 * 8);
            P.ka[kc] = *(const bf16x8*)(Kb + (size_t)(RB + c) * HD + kc * 16 + h2 * 8);
            int jra = jr0 > 2046 ? 2046 : jr0;
            int jr1 = jr0 + 32; int jrb = jr1 > 2046 ? 2046 : jr1;
            P.e0[kc] = *(const bf16x8*)(Eg + (size_t)jra * HD + kc * 16 + h2 * 8);
            P.e1[kc] = *(const bf16x8*)(Eg + (size_t)jrb * HD + kc * 16 + h2 * 8);
        }
        P.v0 = *(const bf16x8*)(Vb + (size_t)vd0 * SEQ + vs8 * 8);
        P.v1 = *(const bf16x8*)(Vb + (size_t)(vd0 + 32) * SEQ + vs8 * 8);
    }

    for (int r0 = 0; r0 < SEQ; r0 += 64) {
        const int buf = (r0 >> 6) & 1;

        // ---- step 1: stage Vt[buf] from prefetched regs ----
        {
            const int kd0 = (vd0 ^ (vd0 >> 3)) & 7;
            *(bf16x8*)&Vt[buf][vd0][(vs8 ^ kd0) * 8] = P.v0;
            const int d1 = vd0 + 32;
            const int kd1 = (d1 ^ (d1 >> 3)) & 7;
            *(bf16x8*)&Vt[buf][d1][(vs8 ^ kd1) * 8] = P.v1;
        }

        // ---- step 2a: S1 + M0/N0 MFMAs ----
        f32x16 s1a, ma0, na0;
        #pragma unroll
        for (int r = 0; r < 16; ++r) { s1a[r] = 0.f; ma0[r] = 0.f; na0[r] = 0.f; }
        __builtin_amdgcn_s_setprio(1);
        #pragma unroll
        for (int kc = 0; kc < 4; ++kc) {
            s1a = __builtin_amdgcn_mfma_f32_32x32x16_bf16(qa[kc], P.kb[kc], s1a, 0, 0, 0);
            ma0 = __builtin_amdgcn_mfma_f32_32x32x16_bf16(qa[kc], P.e0[kc], ma0, 0, 0, 0);
            na0 = __builtin_amdgcn_mfma_f32_32x32x16_bf16(P.ka[kc], P.e0[kc], na0, 0, 0, 0);
        }
        __builtin_amdgcn_s_setprio(0);
        // write S1T (col-major, swizzled): col r = CB+c, 4-row chunks
        {
            const int rcol = CB + c;
            #pragma unroll
            for (int q = 0; q < 4; ++q) {
                const int chunk = (RB >> 2) + 2 * q + h2;
                const int swz = chunk ^ (rcol & 15);
                float4 w4 = make_float4(s1a[4 * q + 0], s1a[4 * q + 1], s1a[4 * q + 2], s1a[4 * q + 3]);
                *(float4*)&S1T[rcol * 64 + swz * 4] = w4;
            }
        }
        {
            const int jc0 = 64 * (wid & 1) + c;
            #pragma unroll
            for (int q = 0; q < 4; ++q) {
                const int lb = RB + 8 * q + 4 * h2;
                ushort4 mw, nw;
                mw.x = f2b(ma0[4 * q + 0]); mw.y = f2b(ma0[4 * q + 1]);
                mw.z = f2b(ma0[4 * q + 2]); mw.w = f2b(ma0[4 * q + 3]);
                nw.x = f2b(na0[4 * q + 0]); nw.y = f2b(na0[4 * q + 1]);
                nw.z = f2b(na0[4 * q + 2]); nw.w = f2b(na0[4 * q + 3]);
                *(ushort4*)&Mt[jc0][lb] = mw;
                *(ushort4*)&Nt[jc0][lb] = nw;
            }
        }
        // ---- step 2b: M1/N1 MFMAs ----
        f32x16 ma1, na1;
        #pragma unroll
        for (int r = 0; r < 16; ++r) { ma1[r] = 0.f; na1[r] = 0.f; }
        __builtin_amdgcn_s_setprio(1);
        #pragma unroll
        for (int kc = 0; kc < 4; ++kc) {
            ma1 = __builtin_amdgcn_mfma_f32_32x32x16_bf16(qa[kc], P.e1[kc], ma1, 0, 0, 0);
            na1 = __builtin_amdgcn_mfma_f32_32x32x16_bf16(P.ka[kc], P.e1[kc], na1, 0, 0, 0);
        }
        __builtin_amdgcn_s_setprio(0);
        {
            const int jc1 = 64 * (wid & 1) + c + 32;
            #pragma unroll
            for (int q = 0; q < 4; ++q) {
                const int lb = RB + 8 * q + 4 * h2;
                ushort4 mw, nw;
                mw.x = f2b(ma1[4 * q + 0]); mw.y = f2b(ma1[4 * q + 1]);
                mw.z = f2b(ma1[4 * q + 2]); mw.w = f2b(ma1[4 * q + 3]);
                nw.x = f2b(na1[4 * q + 0]); nw.y = f2b(na1[4 * q + 1]);
                nw.z = f2b(na1[4 * q + 2]); nw.w = f2b(na1[4 * q + 3]);
                *(ushort4*)&Mt[jc1][lb] = mw;
                *(ushort4*)&Nt[jc1][lb] = nw;
            }
        }

        // ---- step 4: prefetch next tile's K/E/V into regs (latency spans 2 phases) ----
        {
            int r0n = r0 + 64; if (r0n >= SEQ) r0n = 0;
            const int jb = l0 - r0n + 960;
            const int jr0 = jb + 64 * (wid & 1) + c;
            #pragma unroll
            for (int kc = 0; kc < 4; ++kc) {
                P.kb[kc] = *(const bf16x8*)(Kb + (size_t)(r0n + CB + c) * HD + kc * 16 + h2 * 8);
                P.ka[kc] = *(const bf16x8*)(Kb + (size_t)(r0n + RB + c) * HD + kc * 16 + h2 * 8);
                int jra = jr0 > 2046 ? 2046 : jr0;
                int jr1 = jr0 + 32; int jrb = jr1 > 2046 ? 2046 : jr1;
                P.e0[kc] = *(const bf16x8*)(Eg + (size_t)jra * HD + kc * 16 + h2 * 8);
                P.e1[kc] = *(const bf16x8*)(Eg + (size_t)jrb * HD + kc * 16 + h2 * 8);
            }
            P.v0 = *(const bf16x8*)(Vb + (size_t)vd0 * SEQ + r0n + vs8 * 8);
            P.v1 = *(const bf16x8*)(Vb + (size_t)(vd0 + 32) * SEQ + r0n + vs8 * 8);
        }

        __syncthreads();   // BARRIER-A: S1T/Mt/Nt visible

        // ---- step 5: softmax (thread owns row li, cols c0q..c0q+15), log2 domain ----
        float4 mk[4];
        #pragma unroll
        for (int q = 0; q < 4; ++q)
            mk[q] = *(const float4*)(mrow_base + r0 + c0q + 4 * q);

        float sc[16];
        #pragma unroll
        for (int j = 0; j < 16; ++j) {
            const int rr = c0q + j;
            const int jdx = li - rr + 63;
            float s1v = S1T[rr * 64 + (((li >> 2) ^ j) << 2) + (li & 3)];
            float mv = b2f(Mt[jdx][li]);
            float nv = b2f(Nt[jdx][rr]);
            sc[j] = (s1v + mv + nv) * SC2 + g4(mk[j >> 2], j & 3) * LOG2E;
        }
        float tmax = sc[0];
        #pragma unroll
        for (int j = 1; j < 16; ++j) tmax = fmaxf(tmax, sc[j]);
        tmax = fmaxf(tmax, __shfl_xor(tmax, 1));
        tmax = fmaxf(tmax, __shfl_xor(tmax, 2));
        const bool upd = tmax > m_run + DTHR;          // defer-max (T13)
        const float m_new = upd ? tmax : m_run;
        const float corr = upd ? __builtin_amdgcn_exp2f(m_run - m_new) : 1.0f;
        float tsum = 0.f;
        unsigned short pb[16];
        #pragma unroll
        for (int j = 0; j < 16; ++j) {
            float p = __builtin_amdgcn_exp2f(sc[j] - m_new);
            tsum += p;
            pb[j] = f2b(p);
        }
        tsum += __shfl_xor(tsum, 1);
        tsum += __shfl_xor(tsum, 2);
        lsum = lsum * corr + tsum;
        m_run = m_new;
        if ((tid & 3) == 0) Corr[li] = corr;
        #pragma unroll
        for (int sblk = 0; sblk < 2; ++sblk) {
            bf16x8 pv;
            #pragma unroll
            for (int e = 0; e < 8; ++e) pv[e] = (short)pb[sblk * 8 + e];
            const int slot = ((c0q >> 3) + sblk) ^ kli;
            *(bf16x8*)&Pl[li][slot * 8] = pv;
        }

        __syncthreads();   // BARRIER-B: Pl, Corr visible

        // ---- step 6: PV ----
        #pragma unroll
        for (int q = 0; q < 4; ++q) {
            float4 cr = *(const float4*)&Corr[RB + 8 * q + 4 * h2];
            Oa[4 * q + 0] *= cr.x; Oa[4 * q + 1] *= cr.y;
            Oa[4 * q + 2] *= cr.z; Oa[4 * q + 3] *= cr.w;
        }
        const int lrow = RB + c;
        const int drow = CB + c;
        const int klr = (lrow ^ (lrow >> 3)) & 7;
        const int kdr = (drow ^ (drow >> 3)) & 7;
        __builtin_amdgcn_s_setprio(1);
        #pragma unroll
        for (int kc = 0; kc < 4; ++kc) {
            const int slot = kc * 2 + h2;
            bf16x8 pa  = *(const bf16x8*)&Pl[lrow][(slot ^ klr) * 8];
            bf16x8 vbf = *(const bf16x8*)&Vt[buf][drow][(slot ^ kdr) * 8];
            Oa = __builtin_amdgcn_mfma_f32_32x32x16_bf16(pa, vbf, Oa, 0, 0, 0);
        }
        __builtin_amdgcn_s_setprio(0);
    }

    if ((tid & 3) == 0) InvL[li] = 1.0f / lsum;
    __syncthreads();
    #pragma unroll
    for (int q = 0; q < 4; ++q) {
        float4 iv = *(const float4*)&InvL[RB + 8 * q + 4 * h2];
        #pragma unroll
        for (int e = 0; e < 4; ++e) {
            const int l = RB + 8 * q + 4 * h2 + e;
            out[((size_t)b * SEQ + l0 + l) * HID + hh * HD + CB + c] = Oa[4 * q + e] * g4(iv, e);
        }
    }
}

// ------------------------------------------------------------------
extern "C" void kernel_launch(void* const* d_in, const int* in_sizes, int n_in,
                              void* d_out, int out_size, void* d_ws, size_t ws_size,
                              hipStream_t stream) {
    const float* hidden = (const float*)d_in[0];
    const float* mask   = (const float*)d_in[1];
    const float* Wq     = (const float*)d_in[2];
    const float* bq     = (const float*)d_in[3];
    const float* Wk     = (const float*)d_in[4];
    const float* bk     = (const float*)d_in[5];
    const float* Wv     = (const float*)d_in[6];
    const float* bv     = (const float*)d_in[7];
    const float* E      = (const float*)d_in[8];
    float* outp = (float*)d_out;

    unsigned short* ws  = (unsigned short*)d_ws;
    unsigned short* Xbf = ws;                      // 4096*768            = 3145728
    unsigned short* Wt  = ws + 3145728;            // 3*768*768           = 1769472
    unsigned short* Ebf = ws + 4915200;            // 2047*64             = 131008
    unsigned short* qkv = ws + 5046272;            // 3*48*1024*64        = 9437184

    cvt_bf16<<<dim3(1024), 256, 0, stream>>>(hidden, Xbf, 786432);
    cvt_bf16<<<dim3(128),  256, 0, stream>>>(E, Ebf, 32752);
    cvt_wt<<<dim3(12, 12, 3), 256, 0, stream>>>(Wq, Wk, Wv, Wt);
    gemm_qkv<<<dim3(32, 6, 3), 256, 0, stream>>>(Xbf, Wt, bq, bk, bv, qkv);
    const size_t per = (size_t)NB * SEQ * HID;
    attn_mfma<<<dim3(16, 48), 256, 0, stream>>>(qkv, qkv + per, qkv + 2 * per,
                                                Ebf, mask, outp);
}